// Round 2
// baseline (996.376 us; speedup 1.0000x reference)
//
#include <hip/hip_runtime.h>
#include <hip/hip_fp16.h>

#define DEV static __device__ __forceinline__

typedef _Float16 f16;
typedef _Float16 f16x8 __attribute__((ext_vector_type(8)));
typedef _Float16 f16x4 __attribute__((ext_vector_type(4)));
typedef float f32x4 __attribute__((ext_vector_type(4)));

// Problem sizes (fixed)
constexpr int BATCH = 16384;
constexpr int D = 1024;
constexpr int HR = 4096;   // H*R
constexpr int NOUT = 10;

// ---------------------------------------------------------------- converts
__global__ void k_f32_to_f16(const float* __restrict__ src, f16* __restrict__ dst, int n4) {
    int i = blockIdx.x * blockDim.x + threadIdx.x;
    int stride = gridDim.x * blockDim.x;
    for (; i < n4; i += stride) {
        float4 v = reinterpret_cast<const float4*>(src)[i];
        f16x4 h;
        h[0] = (f16)v.x; h[1] = (f16)v.y; h[2] = (f16)v.z; h[3] = (f16)v.w;
        reinterpret_cast<f16x4*>(dst)[i] = h;
    }
}

// ---------------------------------------------------------------- staging helper
DEV void stage16(void* lds, const void* g) {
    __builtin_amdgcn_global_load_lds(
        (const __attribute__((address_space(1))) void*)g,
        (__attribute__((address_space(3))) void*)lds,
        16, 0, 0);
}

// ---------------------------------------------------------------- GEMM1: dual (right & left) projection + bilinear fuse
// Xh:[M,1024] fp16 (row chunk), Wr/Wl:[4096,1024] fp16 (N x K), br/bl:[4096] f32
// inter[b,n] = (sum_k X[b,k]Wr[n,k] + br[n]) * (sum_k X[b,k]Wl[n,k] + bl[n])
__global__ __launch_bounds__(256, 2) void k_gemm_dual(
    const f16* __restrict__ Xh, const f16* __restrict__ Wr, const f16* __restrict__ Wl,
    const float* __restrict__ br, const float* __restrict__ bl,
    f16* __restrict__ inter, int MT)
{
    constexpr int K = 1024;
    constexpr int N = HR;
    __shared__ __align__(16) f16 As[128 * 64];
    __shared__ __align__(16) f16 Brs[128 * 64];
    __shared__ __align__(16) f16 Bls[128 * 64];

    const int tid = threadIdx.x;
    const int mt = blockIdx.x % MT;
    const int nt = blockIdx.x / MT;
    const int m0 = mt * 128, n0 = nt * 128;
    const int w = tid >> 6, lane = tid & 63;
    const int wr_ = w >> 1, wc = w & 1;        // 2x2 waves, each 64x64
    const int fr = lane & 15, fq = lane >> 4;

    f32x4 accR[4][4] = {};
    f32x4 accL[4][4] = {};

    for (int kt = 0; kt < K / 64; ++kt) {
        const int k0 = kt * 64;
#pragma unroll
        for (int i = 0; i < 4; ++i) {
            const int flat = i * 4096 + tid * 16;   // byte offset within 16KB tile
            const int r = flat >> 7;                // 128B per row
            const int cb = flat & 127;
            stage16((char*)As  + flat, (const char*)(Xh + (size_t)(m0 + r) * K + k0) + cb);
            stage16((char*)Brs + flat, (const char*)(Wr + (size_t)(n0 + r) * K + k0) + cb);
            stage16((char*)Bls + flat, (const char*)(Wl + (size_t)(n0 + r) * K + k0) + cb);
        }
        __syncthreads();
#pragma unroll
        for (int kk = 0; kk < 64; kk += 32) {
            f16x8 a[4], pr[4], pl[4];
#pragma unroll
            for (int m = 0; m < 4; ++m)
                a[m] = *reinterpret_cast<const f16x8*>(&As[(wr_ * 64 + m * 16 + fr) * 64 + kk + fq * 8]);
#pragma unroll
            for (int n = 0; n < 4; ++n) {
                pr[n] = *reinterpret_cast<const f16x8*>(&Brs[(wc * 64 + n * 16 + fr) * 64 + kk + fq * 8]);
                pl[n] = *reinterpret_cast<const f16x8*>(&Bls[(wc * 64 + n * 16 + fr) * 64 + kk + fq * 8]);
            }
#pragma unroll
            for (int m = 0; m < 4; ++m)
#pragma unroll
                for (int n = 0; n < 4; ++n) {
                    accR[m][n] = __builtin_amdgcn_mfma_f32_16x16x32_f16(a[m], pr[n], accR[m][n], 0, 0, 0);
                    accL[m][n] = __builtin_amdgcn_mfma_f32_16x16x32_f16(a[m], pl[n], accL[m][n], 0, 0, 0);
                }
        }
        __syncthreads();
    }
    // epilogue: bilinear product, write fp16
#pragma unroll
    for (int n = 0; n < 4; ++n) {
        const int gc = n0 + wc * 64 + n * 16 + fr;
        const float brv = br[gc], blv = bl[gc];
#pragma unroll
        for (int m = 0; m < 4; ++m) {
            const int gr0 = m0 + wr_ * 64 + m * 16 + fq * 4;
#pragma unroll
            for (int j = 0; j < 4; ++j) {
                const float rv = accR[m][n][j] + brv;
                const float lv = accL[m][n][j] + blv;
                inter[(size_t)(gr0 + j) * N + gc] = (f16)(rv * lv);
            }
        }
    }
}

// ---------------------------------------------------------------- GEMM2: expand
// Ain:[M,4096] fp16, Wt:[1024,4096] fp16 (N x K), be:[1024]
// E[b,d] = sum_k Ain[b,k] Wt[d,k] + be[d]   (fp16 out)
__global__ __launch_bounds__(256, 2) void k_gemm_expand(
    const f16* __restrict__ Ain, const f16* __restrict__ Wt,
    const float* __restrict__ be, f16* __restrict__ E, int MT)
{
    constexpr int K = HR;
    __shared__ __align__(16) f16 As[128 * 64];
    __shared__ __align__(16) f16 Bs[128 * 64];

    const int tid = threadIdx.x;
    const int mt = blockIdx.x % MT;
    const int nt = blockIdx.x / MT;
    const int m0 = mt * 128, n0 = nt * 128;
    const int w = tid >> 6, lane = tid & 63;
    const int wr_ = w >> 1, wc = w & 1;
    const int fr = lane & 15, fq = lane >> 4;

    f32x4 acc[4][4] = {};

    for (int kt = 0; kt < K / 64; ++kt) {
        const int k0 = kt * 64;
#pragma unroll
        for (int i = 0; i < 4; ++i) {
            const int flat = i * 4096 + tid * 16;
            const int r = flat >> 7;
            const int cb = flat & 127;
            stage16((char*)As + flat, (const char*)(Ain + (size_t)(m0 + r) * K + k0) + cb);
            stage16((char*)Bs + flat, (const char*)(Wt  + (size_t)(n0 + r) * K + k0) + cb);
        }
        __syncthreads();
#pragma unroll
        for (int kk = 0; kk < 64; kk += 32) {
            f16x8 a[4], b[4];
#pragma unroll
            for (int m = 0; m < 4; ++m)
                a[m] = *reinterpret_cast<const f16x8*>(&As[(wr_ * 64 + m * 16 + fr) * 64 + kk + fq * 8]);
#pragma unroll
            for (int n = 0; n < 4; ++n)
                b[n] = *reinterpret_cast<const f16x8*>(&Bs[(wc * 64 + n * 16 + fr) * 64 + kk + fq * 8]);
#pragma unroll
            for (int m = 0; m < 4; ++m)
#pragma unroll
                for (int n = 0; n < 4; ++n)
                    acc[m][n] = __builtin_amdgcn_mfma_f32_16x16x32_f16(a[m], b[n], acc[m][n], 0, 0, 0);
        }
        __syncthreads();
    }
#pragma unroll
    for (int n = 0; n < 4; ++n) {
        const int gc = n0 + wc * 64 + n * 16 + fr;
        const float bev = be[gc];
#pragma unroll
        for (int m = 0; m < 4; ++m) {
            const int gr0 = m0 + wr_ * 64 + m * 16 + fq * 4;
#pragma unroll
            for (int j = 0; j < 4; ++j)
                E[(size_t)(gr0 + j) * D + gc] = (f16)(acc[m][n][j] + bev);
        }
    }
}

// ---------------------------------------------------------------- residual + LayerNorm (one wave per row)
// X: residual (f32 for block1, f16 for block2), Eb: f16, out: f16
template <typename TR>
__global__ __launch_bounds__(256) void k_ln(
    const TR* __restrict__ X, const f16* __restrict__ Eb,
    const float* __restrict__ g, const float* __restrict__ bb,
    f16* __restrict__ Hh)
{
    const int wid = threadIdx.x >> 6, lane = threadIdx.x & 63;
    const int row = blockIdx.x * 4 + wid;
    const TR* xr = X + (size_t)row * D;
    const f16* er = Eb + (size_t)row * D;
    float v[16];
    float s = 0.f, sq = 0.f;
#pragma unroll
    for (int k = 0; k < 16; ++k) {
        const int c = lane + 64 * k;
        v[k] = (float)xr[c] + (float)er[c];
        s += v[k];
        sq += v[k] * v[k];
    }
#pragma unroll
    for (int off = 32; off; off >>= 1) {
        s += __shfl_down(s, off);
        sq += __shfl_down(sq, off);
    }
    s = __shfl(s, 0);
    sq = __shfl(sq, 0);
    const float mu = s * (1.0f / D);
    const float var = sq * (1.0f / D) - mu * mu;
    const float rs = rsqrtf(var + 1e-5f);
    f16* hh = Hh + (size_t)row * D;
#pragma unroll
    for (int k = 0; k < 16; ++k) {
        const int c = lane + 64 * k;
        const float o = (v[k] - mu) * rs * g[c] + bb[c];
        hh[c] = (f16)o;
    }
}

// ---------------------------------------------------------------- head: out = H @ wf^T + bf  (one wave per row)
__global__ __launch_bounds__(256) void k_head(
    const f16* __restrict__ Hf, const float* __restrict__ Wf,
    const float* __restrict__ bf, float* __restrict__ outp)
{
    __shared__ float wfs[NOUT * D];   // 40KB
    for (int i = threadIdx.x; i < NOUT * D; i += 256) wfs[i] = Wf[i];
    __syncthreads();
    const int wid = threadIdx.x >> 6, lane = threadIdx.x & 63;
    const int row = blockIdx.x * 4 + wid;
    const f16* hr = Hf + (size_t)row * D;
    float hv[16];
#pragma unroll
    for (int k = 0; k < 16; ++k) hv[k] = (float)hr[lane + 64 * k];
#pragma unroll
    for (int j = 0; j < NOUT; ++j) {
        float p = 0.f;
#pragma unroll
        for (int k = 0; k < 16; ++k) p += hv[k] * wfs[j * D + lane + 64 * k];
#pragma unroll
        for (int off = 32; off; off >>= 1) p += __shfl_down(p, off);
        if (lane == 0) outp[(size_t)row * NOUT + j] = p + bf[j];
    }
}

// ---------------------------------------------------------------- launch
extern "C" void kernel_launch(void* const* d_in, const int* in_sizes, int n_in,
                              void* d_out, int out_size, void* d_ws, size_t ws_size,
                              hipStream_t stream) {
    (void)in_sizes; (void)n_in; (void)out_size;
    const float* x   = (const float*)d_in[0];
    const float* wr1 = (const float*)d_in[1];
    const float* br1 = (const float*)d_in[2];
    const float* wl1 = (const float*)d_in[3];
    const float* bl1 = (const float*)d_in[4];
    const float* we1 = (const float*)d_in[5];
    const float* be1 = (const float*)d_in[6];
    const float* g1  = (const float*)d_in[7];
    const float* b1  = (const float*)d_in[8];
    const float* wr2 = (const float*)d_in[9];
    const float* br2 = (const float*)d_in[10];
    const float* wl2 = (const float*)d_in[11];
    const float* bl2 = (const float*)d_in[12];
    const float* we2 = (const float*)d_in[13];
    const float* be2 = (const float*)d_in[14];
    const float* g2  = (const float*)d_in[15];
    const float* b2  = (const float*)d_in[16];
    const float* wf  = (const float*)d_in[17];
    const float* bf  = (const float*)d_in[18];
    float* outp = (float*)d_out;

    constexpr size_t SZ_W16 = (size_t)HR * D * sizeof(f16);    // 8 MB
    constexpr size_t SZ_A16 = (size_t)BATCH * D * sizeof(f16); // 32 MB

    // Fixed-layout buffers: 3 rotating weight bufs + xh + h1h + Eh = 120 MB
    char* p = (char*)d_ws;
    f16* wrh = (f16*)p; p += SZ_W16;
    f16* wlh = (f16*)p; p += SZ_W16;
    f16* weh = (f16*)p; p += SZ_W16;
    f16* xh  = (f16*)p; p += SZ_A16;   // block-1 dual input; reused as h2h
    f16* h1h = (f16*)p; p += SZ_A16;   // ln1 out; block-2 dual input + residual
    f16* Eh  = (f16*)p; p += SZ_A16;   // expand output (per block)
    f16* interh = (f16*)p;             // chunked [CH x HR] fp16
    const size_t base = (size_t)(p - (char*)d_ws);
    const size_t avail = ws_size > base ? ws_size - base : 0;

    int CH = 1024;
    if ((size_t)16384 * HR * sizeof(f16) <= avail) CH = 16384;
    else if ((size_t)8192 * HR * sizeof(f16) <= avail) CH = 8192;
    else if ((size_t)4096 * HR * sizeof(f16) <= avail) CH = 4096;
    else if ((size_t)2048 * HR * sizeof(f16) <= avail) CH = 2048;

    f16* h2h = xh;
    const int nch = BATCH / CH;
    const int MTd = CH / 128;
    const int gDual = MTd * (HR / 128);
    const int gExp  = MTd * (D / 128);

    // ---- block 1 weights + input converts
    k_f32_to_f16<<<2048, 256, 0, stream>>>(x,   xh,  BATCH * D / 4);
    k_f32_to_f16<<<1024, 256, 0, stream>>>(wr1, wrh, HR * D / 4);
    k_f32_to_f16<<<1024, 256, 0, stream>>>(wl1, wlh, HR * D / 4);
    k_f32_to_f16<<<1024, 256, 0, stream>>>(we1, weh, HR * D / 4);

    // ---- block 1
    for (int c = 0; c < nch; ++c) {
        k_gemm_dual<<<gDual, 256, 0, stream>>>(xh + (size_t)c * CH * D, wrh, wlh, br1, bl1, interh, MTd);
        k_gemm_expand<<<gExp, 256, 0, stream>>>(interh, weh, be1, Eh + (size_t)c * CH * D, MTd);
    }
    k_ln<float><<<BATCH / 4, 256, 0, stream>>>(x, Eh, g1, b1, h1h);

    // ---- block 2 weights (rotate into same bufs; stream order makes this safe)
    k_f32_to_f16<<<1024, 256, 0, stream>>>(wr2, wrh, HR * D / 4);
    k_f32_to_f16<<<1024, 256, 0, stream>>>(wl2, wlh, HR * D / 4);
    k_f32_to_f16<<<1024, 256, 0, stream>>>(we2, weh, HR * D / 4);

    // ---- block 2
    for (int c = 0; c < nch; ++c) {
        k_gemm_dual<<<gDual, 256, 0, stream>>>(h1h + (size_t)c * CH * D, wrh, wlh, br2, bl2, interh, MTd);
        k_gemm_expand<<<gExp, 256, 0, stream>>>(interh, weh, be2, Eh + (size_t)c * CH * D, MTd);
    }
    k_ln<f16><<<BATCH / 4, 256, 0, stream>>>(h1h, Eh, g2, b2, h2h);

    // ---- head
    k_head<<<BATCH / 4, 256, 0, stream>>>(h2h, wf, bf, outp);
}

// Round 3
// 994.466 us; speedup vs baseline: 1.0019x; 1.0019x over previous
//
#include <hip/hip_runtime.h>
#include <hip/hip_fp16.h>

#define DEV static __device__ __forceinline__

typedef _Float16 f16;
typedef _Float16 f16x8 __attribute__((ext_vector_type(8)));
typedef _Float16 f16x4 __attribute__((ext_vector_type(4)));
typedef float f32x4 __attribute__((ext_vector_type(4)));

constexpr int BATCH = 16384;
constexpr int D = 1024;
constexpr int HR = 4096;
constexpr int NOUT = 10;

// ---------------------------------------------------------------- converts
__global__ void k_f32_to_f16(const float* __restrict__ src, f16* __restrict__ dst, int n4) {
    int i = blockIdx.x * blockDim.x + threadIdx.x;
    int stride = gridDim.x * blockDim.x;
    for (; i < n4; i += stride) {
        float4 v = reinterpret_cast<const float4*>(src)[i];
        f16x4 h;
        h[0] = (f16)v.x; h[1] = (f16)v.y; h[2] = (f16)v.z; h[3] = (f16)v.w;
        reinterpret_cast<f16x4*>(dst)[i] = h;
    }
}

// ---------------------------------------------------------------- helpers
DEV void stage16(void* lds, const void* g) {
    __builtin_amdgcn_global_load_lds(
        (const __attribute__((address_space(1))) void*)g,
        (__attribute__((address_space(3))) void*)lds,
        16, 0, 0);
}

// Inverse-swizzled global source for a linear LDS dest offset o (16KB unit of
// 128 rows x 128B). LDS linear addr a holds element (row=a>>7, col=(a&127)^((row&7)<<4)).
DEV const char* swz_src(const void* base, int o, int row0, int rowBytes) {
    const int r = o >> 7;
    const int cb = (o & 127) ^ ((r & 7) << 4);
    return (const char*)base + (size_t)(row0 + r) * rowBytes + cb;
}

DEV int xcd_swz(int bid, int nwg) {        // nwg % 8 == 0 in all our grids
    const int cpx = nwg >> 3;
    return (bid & 7) * cpx + (bid >> 3);
}

// ---------------------------------------------------------------- GEMM1: dual projection + bilinear fuse
// Xh:[M,1024], Wr/Wl:[4096,1024] (NxK); inter[b,n] = (X.Wr[n]+br)*(X.Wl[n]+bl)
// Block tile: 128(M) x 128(N), BK=64; 8 waves (2M x 4N), wave tile 64x32 (x2 for R,L).
// LDS: 3 bufs x (A 16KB + Br 16KB + Bl 16KB) = 144KB.
__global__ __launch_bounds__(512, 2) void k_gemm_dual(
    const f16* __restrict__ Xh, const f16* __restrict__ Wr, const f16* __restrict__ Wl,
    const float* __restrict__ br, const float* __restrict__ bl,
    f16* __restrict__ inter, int MT)
{
    extern __shared__ __align__(16) char smem[];
    constexpr int K = 1024, NT = K / 64;
    constexpr int BUF = 48 * 1024;

    const int swz = xcd_swz(blockIdx.x, gridDim.x);
    const int mt = swz % MT, nt = swz / MT;
    const int m0 = mt * 128, n0 = nt * 128;
    const int tid = threadIdx.x;
    const int wid = tid >> 6, lane = tid & 63;
    const int wm = wid >> 2, wn = wid & 3;
    const int fr = lane & 15, fq = lane >> 4;
    const int sw = (fr & 7) << 4;           // read-side swizzle (row&7 == fr&7 always)

    // staging source pointers (2 loads per 16KB unit)
    const int o0 = tid * 16, o1 = tid * 16 + 8192;
    const char* srcA0 = swz_src(Xh, o0, m0, 2048);
    const char* srcA1 = swz_src(Xh, o1, m0, 2048);
    const char* srcR0 = swz_src(Wr, o0, n0, 2048);
    const char* srcR1 = swz_src(Wr, o1, n0, 2048);
    const char* srcL0 = swz_src(Wl, o0, n0, 2048);
    const char* srcL1 = swz_src(Wl, o1, n0, 2048);

    f32x4 accR[4][2] = {};
    f32x4 accL[4][2] = {};

    // prologue: stage tiles 0 and 1 (6 vm-ops each per wave)
    for (int t = 0; t < 2; ++t) {
        char* b = smem + t * BUF;
        const long ko = (long)t * 128;
        stage16(b + o0, srcA0 + ko);          stage16(b + o1, srcA1 + ko);
        stage16(b + 16384 + o0, srcR0 + ko);  stage16(b + 16384 + o1, srcR1 + ko);
        stage16(b + 32768 + o0, srcL0 + ko);  stage16(b + 32768 + o1, srcL1 + ko);
    }
    asm volatile("s_waitcnt vmcnt(6)" ::: "memory");
    __builtin_amdgcn_s_barrier();

    int cur = 0;
    long koff = 256;                          // byte k-offset of tile t+2
    for (int t = 0; t < NT; ++t) {
        char* base = smem + cur * BUF;
        const int stg = cur ? cur - 1 : 2;    // (t+2)%3
        char* nb = smem + stg * BUF;
        const bool pf = (t + 2) < NT;

        f16x8 av[4], bR[2], bL[2];
        // ---------------- phase 0 (ks = 0)
#pragma unroll
        for (int m = 0; m < 4; ++m)
            av[m] = *(const f16x8*)(base + (wm * 64 + m * 16 + fr) * 128 + ((fq * 16) ^ sw));
#pragma unroll
        for (int n = 0; n < 2; ++n) {
            const int ro = (wn * 32 + n * 16 + fr) * 128 + ((fq * 16) ^ sw);
            bR[n] = *(const f16x8*)(base + 16384 + ro);
            bL[n] = *(const f16x8*)(base + 32768 + ro);
        }
        if (pf) {
            stage16(nb + o0, srcA0 + koff);          stage16(nb + o1, srcA1 + koff);
            stage16(nb + 16384 + o0, srcR0 + koff);  stage16(nb + 16384 + o1, srcR1 + koff);
        }
        __builtin_amdgcn_s_barrier();
        __builtin_amdgcn_s_setprio(1);
#pragma unroll
        for (int m = 0; m < 4; ++m)
#pragma unroll
            for (int n = 0; n < 2; ++n) {
                accR[m][n] = __builtin_amdgcn_mfma_f32_16x16x32_f16(av[m], bR[n], accR[m][n], 0, 0, 0);
                accL[m][n] = __builtin_amdgcn_mfma_f32_16x16x32_f16(av[m], bL[n], accL[m][n], 0, 0, 0);
            }
        __builtin_amdgcn_s_setprio(0);
        __builtin_amdgcn_s_barrier();

        // ---------------- phase 1 (ks = 1)
#pragma unroll
        for (int m = 0; m < 4; ++m)
            av[m] = *(const f16x8*)(base + (wm * 64 + m * 16 + fr) * 128 + ((64 + fq * 16) ^ sw));
#pragma unroll
        for (int n = 0; n < 2; ++n) {
            const int ro = (wn * 32 + n * 16 + fr) * 128 + ((64 + fq * 16) ^ sw);
            bR[n] = *(const f16x8*)(base + 16384 + ro);
            bL[n] = *(const f16x8*)(base + 32768 + ro);
        }
        if (pf) {
            stage16(nb + 32768 + o0, srcL0 + koff);  stage16(nb + 32768 + o1, srcL1 + koff);
        }
        __builtin_amdgcn_s_barrier();
        __builtin_amdgcn_s_setprio(1);
#pragma unroll
        for (int m = 0; m < 4; ++m)
#pragma unroll
            for (int n = 0; n < 2; ++n) {
                accR[m][n] = __builtin_amdgcn_mfma_f32_16x16x32_f16(av[m], bR[n], accR[m][n], 0, 0, 0);
                accL[m][n] = __builtin_amdgcn_mfma_f32_16x16x32_f16(av[m], bL[n], accL[m][n], 0, 0, 0);
            }
        __builtin_amdgcn_s_setprio(0);
        if (pf) asm volatile("s_waitcnt vmcnt(6)" ::: "memory");
        else    asm volatile("s_waitcnt vmcnt(0)" ::: "memory");
        __builtin_amdgcn_s_barrier();

        cur = (cur == 2) ? 0 : cur + 1;
        koff += 128;
    }

    // epilogue: bias + bilinear product, fp16 out
#pragma unroll
    for (int n = 0; n < 2; ++n) {
        const int gc = n0 + wn * 32 + n * 16 + fr;
        const float brv = br[gc], blv = bl[gc];
#pragma unroll
        for (int m = 0; m < 4; ++m) {
            const int gr0 = m0 + wm * 64 + m * 16 + fq * 4;
#pragma unroll
            for (int j = 0; j < 4; ++j) {
                const float rv = accR[m][n][j] + brv;
                const float lv = accL[m][n][j] + blv;
                inter[(size_t)(gr0 + j) * HR + gc] = (f16)(rv * lv);
            }
        }
    }
}

// ---------------------------------------------------------------- GEMM2: expand
// Ain:[M,4096], Wt:[1024,4096] (NxK); E = Ain.Wt^T + be (fp16 out)
// Block tile 256(M) x 128(N), BK=64; 8 waves (2M x 4N), wave tile 128x32.
// LDS: 3 bufs x (A 32KB + B 16KB) = 144KB.
__global__ __launch_bounds__(512, 2) void k_gemm_expand(
    const f16* __restrict__ Ain, const f16* __restrict__ Wt,
    const float* __restrict__ be, f16* __restrict__ E, int MT)
{
    extern __shared__ __align__(16) char smem[];
    constexpr int K = HR, NT = K / 64;
    constexpr int BUF = 48 * 1024;

    const int swz = xcd_swz(blockIdx.x, gridDim.x);
    const int mt = swz % MT, nt = swz / MT;
    const int m0 = mt * 256, n0 = nt * 128;
    const int tid = threadIdx.x;
    const int wid = tid >> 6, lane = tid & 63;
    const int wm = wid >> 2, wn = wid & 3;
    const int fr = lane & 15, fq = lane >> 4;
    const int sw = (fr & 7) << 4;

    const int o0 = tid * 16, o1 = tid * 16 + 8192;
    const char* srcA0 = swz_src(Ain, o0, m0, 8192);
    const char* srcA1 = swz_src(Ain, o1, m0, 8192);
    const char* srcA2 = swz_src(Ain, o0, m0 + 128, 8192);
    const char* srcA3 = swz_src(Ain, o1, m0 + 128, 8192);
    const char* srcB0 = swz_src(Wt, o0, n0, 8192);
    const char* srcB1 = swz_src(Wt, o1, n0, 8192);

    f32x4 acc[8][2] = {};

    for (int t = 0; t < 2; ++t) {
        char* b = smem + t * BUF;
        const long ko = (long)t * 128;
        stage16(b + o0, srcA0 + ko);          stage16(b + o1, srcA1 + ko);
        stage16(b + 16384 + o0, srcA2 + ko);  stage16(b + 16384 + o1, srcA3 + ko);
        stage16(b + 32768 + o0, srcB0 + ko);  stage16(b + 32768 + o1, srcB1 + ko);
    }
    asm volatile("s_waitcnt vmcnt(6)" ::: "memory");
    __builtin_amdgcn_s_barrier();

    int cur = 0;
    long koff = 256;
    for (int t = 0; t < NT; ++t) {
        char* base = smem + cur * BUF;
        const int stg = cur ? cur - 1 : 2;
        char* nb = smem + stg * BUF;
        const bool pf = (t + 2) < NT;

        f16x8 av[8], bv[2];
        // ---------------- phase 0 (ks = 0)
#pragma unroll
        for (int m = 0; m < 8; ++m)
            av[m] = *(const f16x8*)(base + (wm * 128 + m * 16 + fr) * 128 + ((fq * 16) ^ sw));
#pragma unroll
        for (int n = 0; n < 2; ++n)
            bv[n] = *(const f16x8*)(base + 32768 + (wn * 32 + n * 16 + fr) * 128 + ((fq * 16) ^ sw));
        if (pf) {
            stage16(nb + o0, srcA0 + koff);          stage16(nb + o1, srcA1 + koff);
            stage16(nb + 16384 + o0, srcA2 + koff);  stage16(nb + 16384 + o1, srcA3 + koff);
        }
        __builtin_amdgcn_s_barrier();
        __builtin_amdgcn_s_setprio(1);
#pragma unroll
        for (int m = 0; m < 8; ++m)
#pragma unroll
            for (int n = 0; n < 2; ++n)
                acc[m][n] = __builtin_amdgcn_mfma_f32_16x16x32_f16(av[m], bv[n], acc[m][n], 0, 0, 0);
        __builtin_amdgcn_s_setprio(0);
        __builtin_amdgcn_s_barrier();

        // ---------------- phase 1 (ks = 1)
#pragma unroll
        for (int m = 0; m < 8; ++m)
            av[m] = *(const f16x8*)(base + (wm * 128 + m * 16 + fr) * 128 + ((64 + fq * 16) ^ sw));
#pragma unroll
        for (int n = 0; n < 2; ++n)
            bv[n] = *(const f16x8*)(base + 32768 + (wn * 32 + n * 16 + fr) * 128 + ((64 + fq * 16) ^ sw));
        if (pf) {
            stage16(nb + 32768 + o0, srcB0 + koff);  stage16(nb + 32768 + o1, srcB1 + koff);
        }
        __builtin_amdgcn_s_barrier();
        __builtin_amdgcn_s_setprio(1);
#pragma unroll
        for (int m = 0; m < 8; ++m)
#pragma unroll
            for (int n = 0; n < 2; ++n)
                acc[m][n] = __builtin_amdgcn_mfma_f32_16x16x32_f16(av[m], bv[n], acc[m][n], 0, 0, 0);
        __builtin_amdgcn_s_setprio(0);
        if (pf) asm volatile("s_waitcnt vmcnt(6)" ::: "memory");
        else    asm volatile("s_waitcnt vmcnt(0)" ::: "memory");
        __builtin_amdgcn_s_barrier();

        cur = (cur == 2) ? 0 : cur + 1;
        koff += 128;
    }

#pragma unroll
    for (int n = 0; n < 2; ++n) {
        const int gc = n0 + wn * 32 + n * 16 + fr;
        const float bev = be[gc];
#pragma unroll
        for (int m = 0; m < 8; ++m) {
            const int gr0 = m0 + wm * 128 + m * 16 + fq * 4;
#pragma unroll
            for (int j = 0; j < 4; ++j)
                E[(size_t)(gr0 + j) * D + gc] = (f16)(acc[m][n][j] + bev);
        }
    }
}

// ---------------------------------------------------------------- residual + LayerNorm
template <typename TR>
__global__ __launch_bounds__(256) void k_ln(
    const TR* __restrict__ X, const f16* __restrict__ Eb,
    const float* __restrict__ g, const float* __restrict__ bb,
    f16* __restrict__ Hh)
{
    const int wid = threadIdx.x >> 6, lane = threadIdx.x & 63;
    const int row = blockIdx.x * 4 + wid;
    const TR* xr = X + (size_t)row * D;
    const f16* er = Eb + (size_t)row * D;
    float v[16];
    float s = 0.f, sq = 0.f;
#pragma unroll
    for (int k = 0; k < 16; ++k) {
        const int c = lane + 64 * k;
        v[k] = (float)xr[c] + (float)er[c];
        s += v[k];
        sq += v[k] * v[k];
    }
#pragma unroll
    for (int off = 32; off; off >>= 1) {
        s += __shfl_down(s, off);
        sq += __shfl_down(sq, off);
    }
    s = __shfl(s, 0);
    sq = __shfl(sq, 0);
    const float mu = s * (1.0f / D);
    const float var = sq * (1.0f / D) - mu * mu;
    const float rs = rsqrtf(var + 1e-5f);
    f16* hh = Hh + (size_t)row * D;
#pragma unroll
    for (int k = 0; k < 16; ++k) {
        const int c = lane + 64 * k;
        const float o = (v[k] - mu) * rs * g[c] + bb[c];
        hh[c] = (f16)o;
    }
}

// ---------------------------------------------------------------- head
__global__ __launch_bounds__(256) void k_head(
    const f16* __restrict__ Hf, const float* __restrict__ Wf,
    const float* __restrict__ bf, float* __restrict__ outp)
{
    __shared__ float wfs[NOUT * D];
    for (int i = threadIdx.x; i < NOUT * D; i += 256) wfs[i] = Wf[i];
    __syncthreads();
    const int wid = threadIdx.x >> 6, lane = threadIdx.x & 63;
    const int row = blockIdx.x * 4 + wid;
    const f16* hr = Hf + (size_t)row * D;
    float hv[16];
#pragma unroll
    for (int k = 0; k < 16; ++k) hv[k] = (float)hr[lane + 64 * k];
#pragma unroll
    for (int j = 0; j < NOUT; ++j) {
        float p = 0.f;
#pragma unroll
        for (int k = 0; k < 16; ++k) p += hv[k] * wfs[j * D + lane + 64 * k];
#pragma unroll
        for (int off = 32; off; off >>= 1) p += __shfl_down(p, off);
        if (lane == 0) outp[(size_t)row * NOUT + j] = p + bf[j];
    }
}

// ---------------------------------------------------------------- launch
extern "C" void kernel_launch(void* const* d_in, const int* in_sizes, int n_in,
                              void* d_out, int out_size, void* d_ws, size_t ws_size,
                              hipStream_t stream) {
    (void)in_sizes; (void)n_in; (void)out_size;
    const float* x   = (const float*)d_in[0];
    const float* wr1 = (const float*)d_in[1];
    const float* br1 = (const float*)d_in[2];
    const float* wl1 = (const float*)d_in[3];
    const float* bl1 = (const float*)d_in[4];
    const float* we1 = (const float*)d_in[5];
    const float* be1 = (const float*)d_in[6];
    const float* g1  = (const float*)d_in[7];
    const float* b1  = (const float*)d_in[8];
    const float* wr2 = (const float*)d_in[9];
    const float* br2 = (const float*)d_in[10];
    const float* wl2 = (const float*)d_in[11];
    const float* bl2 = (const float*)d_in[12];
    const float* we2 = (const float*)d_in[13];
    const float* be2 = (const float*)d_in[14];
    const float* g2  = (const float*)d_in[15];
    const float* b2  = (const float*)d_in[16];
    const float* wf  = (const float*)d_in[17];
    const float* bf  = (const float*)d_in[18];
    float* outp = (float*)d_out;

    constexpr size_t SZ_W16 = (size_t)HR * D * sizeof(f16);
    constexpr size_t SZ_A16 = (size_t)BATCH * D * sizeof(f16);
    constexpr int SMEM = 3 * 48 * 1024;

    hipFuncSetAttribute((const void*)k_gemm_dual,   hipFuncAttributeMaxDynamicSharedMemorySize, SMEM);
    hipFuncSetAttribute((const void*)k_gemm_expand, hipFuncAttributeMaxDynamicSharedMemorySize, SMEM);

    char* p = (char*)d_ws;
    f16* wrh = (f16*)p; p += SZ_W16;
    f16* wlh = (f16*)p; p += SZ_W16;
    f16* weh = (f16*)p; p += SZ_W16;
    f16* xh  = (f16*)p; p += SZ_A16;
    f16* h1h = (f16*)p; p += SZ_A16;
    f16* Eh  = (f16*)p; p += SZ_A16;
    f16* interh = (f16*)p;
    const size_t base = (size_t)(p - (char*)d_ws);
    const size_t avail = ws_size > base ? ws_size - base : 0;

    int CH = 1024;
    if ((size_t)16384 * HR * sizeof(f16) <= avail) CH = 16384;
    else if ((size_t)8192 * HR * sizeof(f16) <= avail) CH = 8192;
    else if ((size_t)4096 * HR * sizeof(f16) <= avail) CH = 4096;
    else if ((size_t)2048 * HR * sizeof(f16) <= avail) CH = 2048;

    f16* h2h = xh;
    const int nch = BATCH / CH;
    const int MTd = CH / 128;
    const int MTe = CH / 256;
    const int gDual = MTd * (HR / 128);
    const int gExp  = MTe * (D / 128);

    k_f32_to_f16<<<2048, 256, 0, stream>>>(x,   xh,  BATCH * D / 4);
    k_f32_to_f16<<<1024, 256, 0, stream>>>(wr1, wrh, HR * D / 4);
    k_f32_to_f16<<<1024, 256, 0, stream>>>(wl1, wlh, HR * D / 4);
    k_f32_to_f16<<<1024, 256, 0, stream>>>(we1, weh, HR * D / 4);

    for (int c = 0; c < nch; ++c) {
        k_gemm_dual<<<gDual, 512, SMEM, stream>>>(xh + (size_t)c * CH * D, wrh, wlh, br1, bl1, interh, MTd);
        k_gemm_expand<<<gExp, 512, SMEM, stream>>>(interh, weh, be1, Eh + (size_t)c * CH * D, MTe);
    }
    k_ln<float><<<BATCH / 4, 256, 0, stream>>>(x, Eh, g1, b1, h1h);

    k_f32_to_f16<<<1024, 256, 0, stream>>>(wr2, wrh, HR * D / 4);
    k_f32_to_f16<<<1024, 256, 0, stream>>>(wl2, wlh, HR * D / 4);
    k_f32_to_f16<<<1024, 256, 0, stream>>>(we2, weh, HR * D / 4);

    for (int c = 0; c < nch; ++c) {
        k_gemm_dual<<<gDual, 512, SMEM, stream>>>(h1h + (size_t)c * CH * D, wrh, wlh, br2, bl2, interh, MTd);
        k_gemm_expand<<<gExp, 512, SMEM, stream>>>(interh, weh, be2, Eh + (size_t)c * CH * D, MTe);
    }
    k_ln<f16><<<BATCH / 4, 256, 0, stream>>>(h1h, Eh, g2, b2, h2h);

    k_head<<<BATCH / 4, 256, 0, stream>>>(h2h, wf, bf, outp);
}

// Round 4
// 969.527 us; speedup vs baseline: 1.0277x; 1.0257x over previous
//
#include <hip/hip_runtime.h>
#include <hip/hip_fp16.h>

#define DEV static __device__ __forceinline__

typedef _Float16 f16;
typedef _Float16 f16x8 __attribute__((ext_vector_type(8)));
typedef _Float16 f16x4 __attribute__((ext_vector_type(4)));
typedef float f32x4 __attribute__((ext_vector_type(4)));

constexpr int BATCH = 16384;
constexpr int D = 1024;
constexpr int HR = 4096;
constexpr int NOUT = 10;

// ---------------------------------------------------------------- converts
__global__ void k_f32_to_f16(const float* __restrict__ src, f16* __restrict__ dst, int n4) {
    int i = blockIdx.x * blockDim.x + threadIdx.x;
    int stride = gridDim.x * blockDim.x;
    for (; i < n4; i += stride) {
        float4 v = reinterpret_cast<const float4*>(src)[i];
        f16x4 h;
        h[0] = (f16)v.x; h[1] = (f16)v.y; h[2] = (f16)v.z; h[3] = (f16)v.w;
        reinterpret_cast<f16x4*>(dst)[i] = h;
    }
}

// ---------------------------------------------------------------- helpers
DEV void stage16(void* lds, const void* g) {
    __builtin_amdgcn_global_load_lds(
        (const __attribute__((address_space(1))) void*)g,
        (__attribute__((address_space(3))) void*)lds,
        16, 0, 0);
}

// Per-thread inverse-swizzled global source pointer for one 16B stage unit.
// LDS region layout: row r (64B = 32 f16 = BK), element (r, cb) stored at
// linear r*64 + (cb ^ (((r>>1)&3)<<4)).  Thread tid covers linear offset
// tid*16 within an 8KB (128-row) region.
DEV const char* src_ptr(const void* base, int tid, int row0, int rowBytes) {
    const int r = tid >> 2;                                    // 0..127
    const int cb = ((tid & 3) << 4) ^ (((r >> 1) & 3) << 4);
    return (const char*)base + (size_t)(row0 + r) * rowBytes + cb;
}

DEV int xcd_swz(int bid, int nwg) {        // nwg % 8 == 0 in all our grids
    const int cpx = nwg >> 3;
    return (bid & 7) * cpx + (bid >> 3);
}

// ---------------------------------------------------------------- GEMM1: dual projection + bilinear fuse
// Xh:[M,1024], Wr/Wl:[4096,1024] (NxK); inter[b,n] = (X.Wr[n]+br)*(X.Wl[n]+bl)
// Block tile 256(M) x 128(N), BK=32; 8 waves (2M x 4N); wave tile 128x32 for
// BOTH R and L (A-frags reused).  LDS ring: 3 bufs x (A 16KB + Br 8KB + Bl 8KB).
__global__ __launch_bounds__(512, 2) void k_gemm_dual(
    const f16* __restrict__ Xh, const f16* __restrict__ Wr, const f16* __restrict__ Wl,
    const float* __restrict__ br, const float* __restrict__ bl,
    f16* __restrict__ inter, int MT)
{
    extern __shared__ __align__(16) char smem[];
    constexpr int K = 1024, NT = K / 32;
    constexpr int BUF = 32 * 1024;

    const int swz = xcd_swz(blockIdx.x, gridDim.x);
    const int mt = swz % MT, nt = swz / MT;
    const int m0 = mt * 256, n0 = nt * 128;
    const int tid = threadIdx.x;
    const int wid = tid >> 6, lane = tid & 63;
    const int wm = wid >> 2, wn = wid & 3;
    const int fr = lane & 15, fq = lane >> 4;
    const int colb = (fq << 4) ^ (((fr >> 1) & 3) << 4);   // read-side swizzle

    // staging source pointers (4 x 16B per thread per tile)
    const char* sA0 = src_ptr(Xh, tid, m0,       2048);
    const char* sA1 = src_ptr(Xh, tid, m0 + 128, 2048);
    const char* sR  = src_ptr(Wr, tid, n0,       2048);
    const char* sL  = src_ptr(Wl, tid, n0,       2048);
    const int dA0 = tid * 16, dA1 = 8192 + tid * 16;
    const int dR = 16384 + tid * 16, dL = 24576 + tid * 16;

    f32x4 accR[8][2] = {};
    f32x4 accL[8][2] = {};

    // prologue: stage tiles 0 and 1
    for (int t = 0; t < 2; ++t) {
        char* b = smem + t * BUF;
        const long ko = (long)t * 64;
        stage16(b + dA0, sA0 + ko);  stage16(b + dA1, sA1 + ko);
        stage16(b + dR,  sR  + ko);  stage16(b + dL,  sL  + ko);
    }
    asm volatile("s_waitcnt vmcnt(4)" ::: "memory");
    __builtin_amdgcn_s_barrier();

    int cur = 0;
    long koff = 128;                          // byte k-offset of tile t+2
    for (int t = 0; t < NT; ++t) {
        char* base = smem + cur * BUF;
        const int stg = cur ? cur - 1 : 2;    // (t+2)%3
        char* nb = smem + stg * BUF;
        const bool pf = (t + 2) < NT;

        f16x8 a[4], bR[2], bL[2];
        // ---------------- phase 0: rows m0-3
#pragma unroll
        for (int m = 0; m < 4; ++m)
            a[m] = *(const f16x8*)(base + (wm * 128 + m * 16 + fr) * 64 + colb);
#pragma unroll
        for (int n = 0; n < 2; ++n) {
            bR[n] = *(const f16x8*)(base + 16384 + (wn * 32 + n * 16 + fr) * 64 + colb);
            bL[n] = *(const f16x8*)(base + 24576 + (wn * 32 + n * 16 + fr) * 64 + colb);
        }
        if (pf) { stage16(nb + dA0, sA0 + koff);  stage16(nb + dA1, sA1 + koff); }
        __builtin_amdgcn_s_barrier();
        __builtin_amdgcn_s_setprio(1);
#pragma unroll
        for (int m = 0; m < 4; ++m)
#pragma unroll
            for (int n = 0; n < 2; ++n) {
                accR[m][n] = __builtin_amdgcn_mfma_f32_16x16x32_f16(a[m], bR[n], accR[m][n], 0, 0, 0);
                accL[m][n] = __builtin_amdgcn_mfma_f32_16x16x32_f16(a[m], bL[n], accL[m][n], 0, 0, 0);
            }
        __builtin_amdgcn_s_setprio(0);
        __builtin_amdgcn_s_barrier();

        // ---------------- phase 1: rows m4-7
        f16x8 a2[4];
#pragma unroll
        for (int m = 0; m < 4; ++m)
            a2[m] = *(const f16x8*)(base + (wm * 128 + (4 + m) * 16 + fr) * 64 + colb);
        if (pf) { stage16(nb + dR, sR + koff);  stage16(nb + dL, sL + koff); }
        __builtin_amdgcn_s_barrier();
        __builtin_amdgcn_s_setprio(1);
#pragma unroll
        for (int m = 0; m < 4; ++m)
#pragma unroll
            for (int n = 0; n < 2; ++n) {
                accR[4 + m][n] = __builtin_amdgcn_mfma_f32_16x16x32_f16(a2[m], bR[n], accR[4 + m][n], 0, 0, 0);
                accL[4 + m][n] = __builtin_amdgcn_mfma_f32_16x16x32_f16(a2[m], bL[n], accL[4 + m][n], 0, 0, 0);
            }
        __builtin_amdgcn_s_setprio(0);
        if (t < NT - 1) {
            if (pf) asm volatile("s_waitcnt vmcnt(4)" ::: "memory");
            else    asm volatile("s_waitcnt vmcnt(0)" ::: "memory");
        }
        __builtin_amdgcn_s_barrier();

        cur = (cur == 2) ? 0 : cur + 1;
        koff += 64;
    }

    // epilogue: bias + bilinear product, fp16 out
#pragma unroll
    for (int n = 0; n < 2; ++n) {
        const int gc = n0 + wn * 32 + n * 16 + fr;
        const float brv = br[gc], blv = bl[gc];
#pragma unroll
        for (int m = 0; m < 8; ++m) {
            const int gr0 = m0 + wm * 128 + m * 16 + fq * 4;
#pragma unroll
            for (int j = 0; j < 4; ++j) {
                const float rv = accR[m][n][j] + brv;
                const float lv = accL[m][n][j] + blv;
                inter[(size_t)(gr0 + j) * HR + gc] = (f16)(rv * lv);
            }
        }
    }
}

// ---------------------------------------------------------------- GEMM2: expand
// Ain:[M,4096], Wt:[1024,4096] (NxK); E = Ain.Wt^T + be (fp16 out)
// Block tile 256(M) x 256(N), BK=32; 8 waves (2M x 4N); wave tile 128x64.
// LDS ring: 3 bufs x (A 16KB + B 16KB).
__global__ __launch_bounds__(512, 2) void k_gemm_expand(
    const f16* __restrict__ Ain, const f16* __restrict__ Wt,
    const float* __restrict__ be, f16* __restrict__ E, int MT)
{
    extern __shared__ __align__(16) char smem[];
    constexpr int K = HR, NT = K / 32;
    constexpr int BUF = 32 * 1024;

    const int swz = xcd_swz(blockIdx.x, gridDim.x);
    const int mt = swz % MT, nt = swz / MT;
    const int m0 = mt * 256, n0 = nt * 256;
    const int tid = threadIdx.x;
    const int wid = tid >> 6, lane = tid & 63;
    const int wm = wid >> 2, wn = wid & 3;
    const int fr = lane & 15, fq = lane >> 4;
    const int colb = (fq << 4) ^ (((fr >> 1) & 3) << 4);

    const char* sA0 = src_ptr(Ain, tid, m0,       8192);
    const char* sA1 = src_ptr(Ain, tid, m0 + 128, 8192);
    const char* sB0 = src_ptr(Wt,  tid, n0,       8192);
    const char* sB1 = src_ptr(Wt,  tid, n0 + 128, 8192);
    const int dA0 = tid * 16, dA1 = 8192 + tid * 16;
    const int dB0 = 16384 + tid * 16, dB1 = 24576 + tid * 16;

    f32x4 acc[8][4] = {};

    for (int t = 0; t < 2; ++t) {
        char* b = smem + t * BUF;
        const long ko = (long)t * 64;
        stage16(b + dA0, sA0 + ko);  stage16(b + dA1, sA1 + ko);
        stage16(b + dB0, sB0 + ko);  stage16(b + dB1, sB1 + ko);
    }
    asm volatile("s_waitcnt vmcnt(4)" ::: "memory");
    __builtin_amdgcn_s_barrier();

    int cur = 0;
    long koff = 128;
    for (int t = 0; t < NT; ++t) {
        char* base = smem + cur * BUF;
        const int stg = cur ? cur - 1 : 2;
        char* nb = smem + stg * BUF;
        const bool pf = (t + 2) < NT;

        f16x8 a[4], bv[4];
        // ---------------- phase 0: rows m0-3
#pragma unroll
        for (int m = 0; m < 4; ++m)
            a[m] = *(const f16x8*)(base + (wm * 128 + m * 16 + fr) * 64 + colb);
#pragma unroll
        for (int n = 0; n < 4; ++n)
            bv[n] = *(const f16x8*)(base + 16384 + (wn * 64 + n * 16 + fr) * 64 + colb);
        if (pf) { stage16(nb + dA0, sA0 + koff);  stage16(nb + dA1, sA1 + koff); }
        __builtin_amdgcn_s_barrier();
        __builtin_amdgcn_s_setprio(1);
#pragma unroll
        for (int m = 0; m < 4; ++m)
#pragma unroll
            for (int n = 0; n < 4; ++n)
                acc[m][n] = __builtin_amdgcn_mfma_f32_16x16x32_f16(a[m], bv[n], acc[m][n], 0, 0, 0);
        __builtin_amdgcn_s_setprio(0);
        __builtin_amdgcn_s_barrier();

        // ---------------- phase 1: rows m4-7
        f16x8 a2[4];
#pragma unroll
        for (int m = 0; m < 4; ++m)
            a2[m] = *(const f16x8*)(base + (wm * 128 + (4 + m) * 16 + fr) * 64 + colb);
        if (pf) { stage16(nb + dB0, sB0 + koff);  stage16(nb + dB1, sB1 + koff); }
        __builtin_amdgcn_s_barrier();
        __builtin_amdgcn_s_setprio(1);
#pragma unroll
        for (int m = 0; m < 4; ++m)
#pragma unroll
            for (int n = 0; n < 4; ++n)
                acc[4 + m][n] = __builtin_amdgcn_mfma_f32_16x16x32_f16(a2[m], bv[n], acc[4 + m][n], 0, 0, 0);
        __builtin_amdgcn_s_setprio(0);
        if (t < NT - 1) {
            if (pf) asm volatile("s_waitcnt vmcnt(4)" ::: "memory");
            else    asm volatile("s_waitcnt vmcnt(0)" ::: "memory");
        }
        __builtin_amdgcn_s_barrier();

        cur = (cur == 2) ? 0 : cur + 1;
        koff += 64;
    }

#pragma unroll
    for (int n = 0; n < 4; ++n) {
        const int gc = n0 + wn * 64 + n * 16 + fr;
        const float bev = be[gc];
#pragma unroll
        for (int m = 0; m < 8; ++m) {
            const int gr0 = m0 + wm * 128 + m * 16 + fq * 4;
#pragma unroll
            for (int j = 0; j < 4; ++j)
                E[(size_t)(gr0 + j) * D + gc] = (f16)(acc[m][n][j] + bev);
        }
    }
}

// ---------------------------------------------------------------- residual + LayerNorm
template <typename TR>
__global__ __launch_bounds__(256) void k_ln(
    const TR* __restrict__ X, const f16* __restrict__ Eb,
    const float* __restrict__ g, const float* __restrict__ bb,
    f16* __restrict__ Hh)
{
    const int wid = threadIdx.x >> 6, lane = threadIdx.x & 63;
    const int row = blockIdx.x * 4 + wid;
    const TR* xr = X + (size_t)row * D;
    const f16* er = Eb + (size_t)row * D;
    float v[16];
    float s = 0.f, sq = 0.f;
#pragma unroll
    for (int k = 0; k < 16; ++k) {
        const int c = lane + 64 * k;
        v[k] = (float)xr[c] + (float)er[c];
        s += v[k];
        sq += v[k] * v[k];
    }
#pragma unroll
    for (int off = 32; off; off >>= 1) {
        s += __shfl_down(s, off);
        sq += __shfl_down(sq, off);
    }
    s = __shfl(s, 0);
    sq = __shfl(sq, 0);
    const float mu = s * (1.0f / D);
    const float var = sq * (1.0f / D) - mu * mu;
    const float rs = rsqrtf(var + 1e-5f);
    f16* hh = Hh + (size_t)row * D;
#pragma unroll
    for (int k = 0; k < 16; ++k) {
        const int c = lane + 64 * k;
        const float o = (v[k] - mu) * rs * g[c] + bb[c];
        hh[c] = (f16)o;
    }
}

// ---------------------------------------------------------------- head
__global__ __launch_bounds__(256) void k_head(
    const f16* __restrict__ Hf, const float* __restrict__ Wf,
    const float* __restrict__ bf, float* __restrict__ outp)
{
    __shared__ float wfs[NOUT * D];
    for (int i = threadIdx.x; i < NOUT * D; i += 256) wfs[i] = Wf[i];
    __syncthreads();
    const int wid = threadIdx.x >> 6, lane = threadIdx.x & 63;
    const int row = blockIdx.x * 4 + wid;
    const f16* hr = Hf + (size_t)row * D;
    float hv[16];
#pragma unroll
    for (int k = 0; k < 16; ++k) hv[k] = (float)hr[lane + 64 * k];
#pragma unroll
    for (int j = 0; j < NOUT; ++j) {
        float p = 0.f;
#pragma unroll
        for (int k = 0; k < 16; ++k) p += hv[k] * wfs[j * D + lane + 64 * k];
#pragma unroll
        for (int off = 32; off; off >>= 1) p += __shfl_down(p, off);
        if (lane == 0) outp[(size_t)row * NOUT + j] = p + bf[j];
    }
}

// ---------------------------------------------------------------- launch
extern "C" void kernel_launch(void* const* d_in, const int* in_sizes, int n_in,
                              void* d_out, int out_size, void* d_ws, size_t ws_size,
                              hipStream_t stream) {
    (void)in_sizes; (void)n_in; (void)out_size;
    const float* x   = (const float*)d_in[0];
    const float* wr1 = (const float*)d_in[1];
    const float* br1 = (const float*)d_in[2];
    const float* wl1 = (const float*)d_in[3];
    const float* bl1 = (const float*)d_in[4];
    const float* we1 = (const float*)d_in[5];
    const float* be1 = (const float*)d_in[6];
    const float* g1  = (const float*)d_in[7];
    const float* b1  = (const float*)d_in[8];
    const float* wr2 = (const float*)d_in[9];
    const float* br2 = (const float*)d_in[10];
    const float* wl2 = (const float*)d_in[11];
    const float* bl2 = (const float*)d_in[12];
    const float* we2 = (const float*)d_in[13];
    const float* be2 = (const float*)d_in[14];
    const float* g2  = (const float*)d_in[15];
    const float* b2  = (const float*)d_in[16];
    const float* wf  = (const float*)d_in[17];
    const float* bf  = (const float*)d_in[18];
    float* outp = (float*)d_out;

    constexpr size_t SZ_W16 = (size_t)HR * D * sizeof(f16);
    constexpr size_t SZ_A16 = (size_t)BATCH * D * sizeof(f16);
    constexpr int SMEM = 3 * 32 * 1024;

    hipFuncSetAttribute((const void*)k_gemm_dual,   hipFuncAttributeMaxDynamicSharedMemorySize, SMEM);
    hipFuncSetAttribute((const void*)k_gemm_expand, hipFuncAttributeMaxDynamicSharedMemorySize, SMEM);

    char* p = (char*)d_ws;
    f16* wrh = (f16*)p; p += SZ_W16;
    f16* wlh = (f16*)p; p += SZ_W16;
    f16* weh = (f16*)p; p += SZ_W16;
    f16* xh  = (f16*)p; p += SZ_A16;
    f16* h1h = (f16*)p; p += SZ_A16;
    f16* Eh  = (f16*)p; p += SZ_A16;
    f16* interh = (f16*)p;
    const size_t base = (size_t)(p - (char*)d_ws);
    const size_t avail = ws_size > base ? ws_size - base : 0;

    int CH = 1024;
    if ((size_t)16384 * HR * sizeof(f16) <= avail) CH = 16384;
    else if ((size_t)8192 * HR * sizeof(f16) <= avail) CH = 8192;
    else if ((size_t)4096 * HR * sizeof(f16) <= avail) CH = 4096;
    else if ((size_t)2048 * HR * sizeof(f16) <= avail) CH = 2048;

    f16* h2h = xh;
    const int nch = BATCH / CH;
    const int MT = CH / 256;                 // 256-row M-tiles for both GEMMs
    const int gDual = MT * (HR / 128);
    const int gExp  = MT * (D / 256);

    k_f32_to_f16<<<2048, 256, 0, stream>>>(x,   xh,  BATCH * D / 4);
    k_f32_to_f16<<<1024, 256, 0, stream>>>(wr1, wrh, HR * D / 4);
    k_f32_to_f16<<<1024, 256, 0, stream>>>(wl1, wlh, HR * D / 4);
    k_f32_to_f16<<<1024, 256, 0, stream>>>(we1, weh, HR * D / 4);

    for (int c = 0; c < nch; ++c) {
        k_gemm_dual<<<gDual, 512, SMEM, stream>>>(xh + (size_t)c * CH * D, wrh, wlh, br1, bl1, interh, MT);
        k_gemm_expand<<<gExp, 512, SMEM, stream>>>(interh, weh, be1, Eh + (size_t)c * CH * D, MT);
    }
    k_ln<float><<<BATCH / 4, 256, 0, stream>>>(x, Eh, g1, b1, h1h);

    k_f32_to_f16<<<1024, 256, 0, stream>>>(wr2, wrh, HR * D / 4);
    k_f32_to_f16<<<1024, 256, 0, stream>>>(wl2, wlh, HR * D / 4);
    k_f32_to_f16<<<1024, 256, 0, stream>>>(we2, weh, HR * D / 4);

    for (int c = 0; c < nch; ++c) {
        k_gemm_dual<<<gDual, 512, SMEM, stream>>>(h1h + (size_t)c * CH * D, wrh, wlh, br2, bl2, interh, MT);
        k_gemm_expand<<<gExp, 512, SMEM, stream>>>(interh, weh, be2, Eh + (size_t)c * CH * D, MT);
    }
    k_ln<f16><<<BATCH / 4, 256, 0, stream>>>(h1h, Eh, g2, b2, h2h);

    k_head<<<BATCH / 4, 256, 0, stream>>>(h2h, wf, bf, outp);
}